// Round 9
// baseline (209.632 us; speedup 1.0000x reference)
//
#include <hip/hip_runtime.h>
#include <math.h>

#define B 16
#define C 128
#define H 32
#define W 512

typedef short bf16x4 __attribute__((ext_vector_type(4)));
typedef short bf16x8 __attribute__((ext_vector_type(8)));
typedef float f32x4 __attribute__((ext_vector_type(4)));

static __device__ inline unsigned short f2bf(float f) {
    unsigned u = __builtin_bit_cast(unsigned, f);
    u += 0x7fffu + ((u >> 16) & 1u);          // RNE
    return (unsigned short)(u >> 16);
}
// pack (lo=a, hi=b) as 2xbf16 in one u32 (RNE via HW cvt_pk)
static __device__ inline unsigned pack2(float a, float b) {
    unsigned u;
    asm("v_cvt_pk_bf16_f32 %0, %1, %2" : "=v"(u) : "v"(a), "v"(b));
    return u;
}
static __device__ inline float bflo(unsigned u) {
    return __builtin_bit_cast(float, u << 16);
}
static __device__ inline float bfhi(unsigned u) {
    return __builtin_bit_cast(float, u & 0xffff0000u);
}

// ---------------- prep: wg [128][64][3] f32 -> wT [2][3][64][64] bf16 ----------------
__global__ __launch_bounds__(256) void prep_wT(const float* __restrict__ wg,
                                               unsigned short* __restrict__ wT) {
    const int e = blockIdx.x * 256 + threadIdx.x;   // 24576 total
    if (e >= 24576) return;
    const int g   = e / 12288;
    const int rem = e - g * 12288;
    const int tap = rem >> 12;
    const int o   = (rem >> 6) & 63;
    const int ci  = rem & 63;
    wT[e] = f2bf(wg[((size_t)(g * 64 + o) * 64 + ci) * 3 + tap]);
}

// ---------------- Kernel A: grouped (1x3) conv via bf16 MFMA (swapped operands) -----
// Block = (g, wq in [0,16), b): 64 o x 32 w x ALL 32 h. 512 blocks = 2/CU.
// A = x (LDS, w-major [34 rows][144 B]), B = weights (regs). D[w][o]: lane owns
// o = col and 4 consecutive w -> float4 y stores. Double-buffered, loads 2-h ahead.
// Fused: pool-H complete (regs -> pool2), pool-W partial (pool3p u32-packed, 16-way),
// pool-C partial (pool1p u32-packed, 2-way).
__global__ __launch_bounds__(256) void conv_mfma(
    const float* __restrict__ x, const unsigned short* __restrict__ wT,
    float* __restrict__ y, unsigned* __restrict__ pool3p,
    unsigned* __restrict__ pool1p, float* __restrict__ pool2) {
    __shared__ __align__(16) char xsb[2][34 * 144];   // 9,792 B
    __shared__ float pcm[4 * 32];                     // 512 B
    __shared__ float pcs[4 * 32];                     // 512 B

    const int bx = blockIdx.x;          // g*16 + wq
    const int g  = bx >> 4;
    const int wq = bx & 15;
    const int b  = blockIdx.y;
    const int t  = threadIdx.x;
    const int lane = t & 63;
    const int col  = lane & 15;         // o sub-index (N of MFMA)
    const int q    = lane >> 4;         // k-group / w quad
    const int wave = t >> 6;            // o-tile 0..3

    // ---- weight B-fragments (same register layout as before the swap) ----
    const unsigned short* wA =
        wT + (size_t)g * 12288 + wave * 1024 + col * 64 + q * 8;
    bf16x8 wfr[3][2];
#pragma unroll
    for (int tap = 0; tap < 3; ++tap)
#pragma unroll
        for (int kk = 0; kk < 2; ++kk)
            wfr[tap][kk] = *(const bf16x8*)(wA + tap * 4096 + kk * 32);

    // ---- staging state: thread stages 2 ci x 4 w ----
    float a[2][4];
    float hv = 0.f;
    const int w0l = (t & 7) * 4;        // local w 0..28
    const int ci0 = (t >> 3) * 2;       // ci 0..62
    const float* xb0 = x + (size_t)(b * C + g * 64 + ci0) * (H * W) + wq * 32 + w0l;
    const int side = (t >> 6) & 1;      // halo side (valid t<128)
    const int hci  = t & 63;
    const int gw   = wq * 32 + (side ? 32 : -1);
    const bool hvalid = (t < 128) && (side ? (wq < 15) : (wq > 0));
    const float* xh0 = x + (size_t)(b * C + g * 64 + hci) * (H * W) + gw;

    auto LOADX = [&](int h) {
        const float4 v0 = *(const float4*)(xb0 + h * W);
        const float4 v1 = *(const float4*)(xb0 + (size_t)(H * W) + h * W);
        a[0][0] = v0.x; a[0][1] = v0.y; a[0][2] = v0.z; a[0][3] = v0.w;
        a[1][0] = v1.x; a[1][1] = v1.y; a[1][2] = v1.z; a[1][3] = v1.w;
        hv = hvalid ? xh0[h * W] : 0.f;
    };
    auto WRITEX = [&](char* buf) {
#pragma unroll
        for (int j = 0; j < 4; ++j)
            *(unsigned*)(buf + (size_t)(w0l + j + 1) * 144 + ci0 * 2) =
                pack2(a[0][j], a[1][j]);
        if (t < 128)
            *(unsigned short*)(buf + (size_t)(side ? 33 : 0) * 144 + hci * 2) = f2bf(hv);
    };

    // ---- pool-H accumulators (persist across all 32 h) ----
    f32x4 mH[2], sH[2];
#pragma unroll
    for (int wt = 0; wt < 2; ++wt) {
        mH[wt] = (f32x4){-INFINITY, -INFINITY, -INFINITY, -INFINITY};
        sH[wt] = (f32x4){0.f, 0.f, 0.f, 0.f};
    }

    // ---- pipeline prologue ----
    LOADX(0);
    WRITEX(xsb[0]);
    LOADX(1);
    __syncthreads();

    for (int h = 0; h < H; ++h) {
        const int cur = h & 1;

        // ---- MFMA: A = x fragment (lane: w-row = col, ci = kk*32 + q*8) ----
        f32x4 acc[2];
        acc[0] = (f32x4){0.f, 0.f, 0.f, 0.f};
        acc[1] = (f32x4){0.f, 0.f, 0.f, 0.f};
        {
            const char* ab = xsb[cur] + q * 16;
#pragma unroll
            for (int wt = 0; wt < 2; ++wt)
#pragma unroll
                for (int kk = 0; kk < 2; ++kk)
#pragma unroll
                    for (int tap = 0; tap < 3; ++tap) {
                        const bf16x8 xf = *(const bf16x8*)(
                            ab + (size_t)(wt * 16 + col + tap) * 144 + kk * 64);
                        acc[wt] = __builtin_amdgcn_mfma_f32_16x16x32_bf16(
                            xf, wfr[tap][kk], acc[wt], 0, 0, 0);
                    }
        }

        // ---- store y: o = g*64+wave*16+col, w = wq*32 + wt*16 + q*4 + r ----
        {
            float* yb = y + ((size_t)(b * C + g * 64 + wave * 16 + col) * H + h) * W +
                        wq * 32 + q * 4;
            *(f32x4*)yb        = acc[0];
            *(f32x4*)(yb + 16) = acc[1];
        }

        // ---- pool-H accumulate ----
#pragma unroll
        for (int wt = 0; wt < 2; ++wt)
#pragma unroll
            for (int r = 0; r < 4; ++r) {
                mH[wt][r] = fmaxf(mH[wt][r], acc[wt][r]);
                sH[wt][r] += acc[wt][r];
            }

        // ---- pool-W (this block's 32 w, per o) -> pool3p ----
        {
            float m = acc[0][0], s = acc[0][0];
            m = fmaxf(fmaxf(m, acc[0][1]), fmaxf(acc[0][2], acc[0][3]));
            s += acc[0][1] + acc[0][2] + acc[0][3];
#pragma unroll
            for (int r = 0; r < 4; ++r) {
                m = fmaxf(m, acc[1][r]);
                s += acc[1][r];
            }
            m = fmaxf(m, __shfl_xor(m, 16)); s += __shfl_xor(s, 16);
            m = fmaxf(m, __shfl_xor(m, 32)); s += __shfl_xor(s, 32);
            if (lane < 16)
                pool3p[((size_t)(wq * B + b) * H + h) * C + g * 64 + wave * 16 + lane] =
                    pack2(m, s);
        }
        // ---- pool-C (this wave's 16 o, per w): reduce across col lanes ----
        {
            float cm[2][4], cs[2][4];
#pragma unroll
            for (int wt = 0; wt < 2; ++wt)
#pragma unroll
                for (int r = 0; r < 4; ++r) { cm[wt][r] = acc[wt][r]; cs[wt][r] = acc[wt][r]; }
#pragma unroll
            for (int off = 1; off <= 8; off <<= 1)
#pragma unroll
                for (int wt = 0; wt < 2; ++wt)
#pragma unroll
                    for (int r = 0; r < 4; ++r) {
                        cm[wt][r] = fmaxf(cm[wt][r], __shfl_xor(cm[wt][r], off));
                        cs[wt][r] += __shfl_xor(cs[wt][r], off);
                    }
            if (col == 0)
#pragma unroll
                for (int wt = 0; wt < 2; ++wt)
#pragma unroll
                    for (int r = 0; r < 4; ++r) {
                        pcm[wave * 32 + wt * 16 + q * 4 + r] = cm[wt][r];
                        pcs[wave * 32 + wt * 16 + q * 4 + r] = cs[wt][r];
                    }
        }

        // ---- pipeline: write next-h LDS from regs, issue loads 2 ahead ----
        if (h < H - 1) WRITEX(xsb[cur ^ 1]);
        if (h < H - 2) LOADX(h + 2);
        __syncthreads();

        // ---- pool-C combine across 4 waves -> pool1p ----
        if (t < 32) {
            float m0 = pcm[t], s0 = pcs[t];
#pragma unroll
            for (int ot = 1; ot < 4; ++ot) {
                m0 = fmaxf(m0, pcm[ot * 32 + t]);
                s0 += pcs[ot * 32 + t];
            }
            pool1p[((size_t)(g * B + b) * H + h) * W + wq * 32 + t] = pack2(m0, s0);
        }
        __syncthreads();
    }

    // ---- pool-H final write -> pool2 [B,2,C,W] (complete, float4) ----
    {
        const int o = g * 64 + wave * 16 + col;
        float* p2m = pool2 + ((size_t)(b * 2 + 0) * C + o) * W + wq * 32 + q * 4;
        float* p2s = pool2 + ((size_t)(b * 2 + 1) * C + o) * W + wq * 32 + q * 4;
#pragma unroll
        for (int wt = 0; wt < 2; ++wt) {
            *(f32x4*)(p2m + wt * 16) = mH[wt];
            f32x4 sv = sH[wt];
            sv[0] *= (1.f / H); sv[1] *= (1.f / H);
            sv[2] *= (1.f / H); sv[3] *= (1.f / H);
            *(f32x4*)(p2s + wt * 16) = sv;
        }
    }
}

// ---------------- combine pool1 partials (2 groups, u32-packed) -> pool1 ----------------
__global__ __launch_bounds__(256) void combine_pool1(const unsigned* __restrict__ p1p,
                                                     float* __restrict__ pool1) {
    const int n = blockIdx.x * 256 + threadIdx.x;   // over B*H*W/4
    const int idx4 = n * 4;
    const uint4 u0 = *(const uint4*)(p1p + idx4);
    const uint4 u1 = *(const uint4*)(p1p + 262144 + idx4);
    const int b = idx4 >> 14;                       // H*W = 16384
    const int o = idx4 & 16383;
    float4 m, s;
    const float k = 1.f / C;
    m.x = fmaxf(bflo(u0.x), bflo(u1.x)); s.x = (bfhi(u0.x) + bfhi(u1.x)) * k;
    m.y = fmaxf(bflo(u0.y), bflo(u1.y)); s.y = (bfhi(u0.y) + bfhi(u1.y)) * k;
    m.z = fmaxf(bflo(u0.z), bflo(u1.z)); s.z = (bfhi(u0.z) + bfhi(u1.z)) * k;
    m.w = fmaxf(bflo(u0.w), bflo(u1.w)); s.w = (bfhi(u0.w) + bfhi(u1.w)) * k;
    *(float4*)(pool1 + ((size_t)(b * 2 + 0) * H * W) + o) = m;
    *(float4*)(pool1 + ((size_t)(b * 2 + 1) * H * W) + o) = s;
}

// ---------------- combine pool3 partials (16 wq, u32-packed) -> pool3 ----------------
__global__ __launch_bounds__(256) void combine_pool3(const unsigned* __restrict__ p3p,
                                                     float* __restrict__ pool3) {
    const int n = blockIdx.x * 256 + threadIdx.x;   // over B*H*C = 65536
    const int b = n >> 12;
    const int o = n & 4095;                          // h*C + c
    float m = -INFINITY, s = 0.f;
#pragma unroll
    for (int wq = 0; wq < 16; ++wq) {
        const unsigned u = p3p[(size_t)(wq * B + b) * 4096 + o];
        m = fmaxf(m, bflo(u));
        s += bfhi(u);
    }
    pool3[((size_t)(b * 2 + 0) * H * C) + o] = m;
    pool3[((size_t)(b * 2 + 1) * H * C) + o] = s * (1.f / W);
}

// ---------------- 7x7 conv (2->1 ch) + sigmoid, 4 outputs/thread ----------------
__global__ __launch_bounds__(256) void conv7_sig(const float* __restrict__ pin,
                                                 const float* __restrict__ wgt,
                                                 float* __restrict__ sout,
                                                 int P, int Q, int total4) {
    const int n = blockIdx.x * 256 + threadIdx.x;   // over B*P*Q/4
    if (n >= total4) return;
    const int q4   = Q >> 2;
    const int q0   = (n % q4) * 4;
    const int rest = n / q4;
    const int p    = rest % P;
    const int b    = rest / P;
    float acc0 = 0.f, acc1 = 0.f, acc2 = 0.f, acc3 = 0.f;
#pragma unroll
    for (int c2 = 0; c2 < 2; ++c2) {
#pragma unroll
        for (int i = 0; i < 7; ++i) {
            const int pp = p + i - 3;
            if (pp < 0 || pp >= P) continue;
            const float* row = pin + ((size_t)(b * 2 + c2) * P + pp) * Q;
            float win[10];
#pragma unroll
            for (int j = 0; j < 10; ++j) {
                const int qq = q0 + j - 3;
                win[j] = (qq >= 0 && qq < Q) ? row[qq] : 0.f;
            }
            const float* wr = wgt + c2 * 49 + i * 7;
#pragma unroll
            for (int j = 0; j < 7; ++j) {
                const float wv = wr[j];
                acc0 += win[j]     * wv;
                acc1 += win[j + 1] * wv;
                acc2 += win[j + 2] * wv;
                acc3 += win[j + 3] * wv;
            }
        }
    }
    float4 o;
    o.x = 1.f / (1.f + expf(-acc0));
    o.y = 1.f / (1.f + expf(-acc1));
    o.z = 1.f / (1.f + expf(-acc2));
    o.w = 1.f / (1.f + expf(-acc3));
    *(float4*)(sout + (size_t)n * 4) = o;
}

// ---------------- out = y * (s1+s2+s3)/3, in place ----------------
__global__ __launch_bounds__(256) void final_mul(float* __restrict__ y,
                                                 const float* __restrict__ s1,
                                                 const float* __restrict__ s2,
                                                 const float* __restrict__ s3) {
    const int n   = blockIdx.x * 256 + threadIdx.x;  // per float4
    const int j   = n & 127;
    const int row = n >> 7;                          // (b*C+c)*H + h
    const int h = row & 31, c = (row >> 5) & 127, b = row >> 12;
    const int w0 = j << 2;
    float4 yv = *(float4*)(y + (size_t)row * W + w0);
    const float4 v1 = *(const float4*)(s1 + ((size_t)b * H + h) * W + w0);
    const float4 v2 = *(const float4*)(s2 + ((size_t)b * C + c) * W + w0);
    const float  g3 = s3[((size_t)b * H + h) * C + c];
    const float k = 1.f / 3.f;
    float4 o;
    o.x = yv.x * (v1.x + v2.x + g3) * k;
    o.y = yv.y * (v1.y + v2.y + g3) * k;
    o.z = yv.z * (v1.z + v2.z + g3) * k;
    o.w = yv.w * (v1.w + v2.w + g3) * k;
    *(float4*)(y + (size_t)row * W + w0) = o;
}

extern "C" void kernel_launch(void* const* d_in, const int* in_sizes, int n_in,
                              void* d_out, int out_size, void* d_ws, size_t ws_size,
                              hipStream_t stream) {
    const float* x  = (const float*)d_in[0];
    const float* wg = (const float*)d_in[1];
    const float* w1 = (const float*)d_in[2];
    const float* w2 = (const float*)d_in[3];
    const float* w3 = (const float*)d_in[4];
    float* y  = (float*)d_out;       // y lives in d_out; final multiply is in-place
    float* ws = (float*)d_ws;

    // Workspace (float-slot offsets), total 4,337,664 floats = 17.4 MB:
    //  [0,       524288): pool1p u32 [2][B][H][W]   -> later s1 @0, s3 @262144
    //  [524288, 1572864): pool3p u32 [16][B][H][C]  -> later s2 @524288
    //  [1572864,3670016): pool2 f32 [B][2][C][W]  (written directly by conv)
    //  [3670016,4194304): pool1 f32 [B][2][H][W]
    //  [4194304,4325376): pool3 f32 [B][2][H][C]
    //  [4325376,4337664): wT (24576 bf16)
    unsigned* pool1p = (unsigned*)ws;
    unsigned* pool3p = (unsigned*)(ws + 524288);
    float* pool2 = ws + 1572864;
    float* pool1 = ws + 3670016;
    float* pool3 = ws + 4194304;
    unsigned short* wT = (unsigned short*)(ws + 4325376);
    float* s1 = ws;
    float* s3 = ws + 262144;
    float* s2 = ws + 524288;

    prep_wT<<<dim3(96), 256, 0, stream>>>(wg, wT);
    conv_mfma<<<dim3(32, 16), 256, 0, stream>>>(x, wT, y, pool3p, pool1p, pool2);

    combine_pool1<<<dim3(256), 256, 0, stream>>>(pool1p, pool1);
    combine_pool3<<<dim3(256), 256, 0, stream>>>(pool3p, pool3);

    conv7_sig<<<dim3(256), 256, 0, stream>>>(pool1, w1, s1, H, W, 65536);
    conv7_sig<<<dim3(1024), 256, 0, stream>>>(pool2, w2, s2, C, W, 262144);
    conv7_sig<<<dim3(64), 256, 0, stream>>>(pool3, w3, s3, H, C, 16384);

    final_mul<<<dim3((B * C * H * W / 4) / 256), 256, 0, stream>>>(y, s1, s2, s3);
}

// Round 10
// 177.236 us; speedup vs baseline: 1.1828x; 1.1828x over previous
//
#include <hip/hip_runtime.h>
#include <math.h>

#define B 16
#define C 128
#define H 32
#define W 512

typedef short bf16x4 __attribute__((ext_vector_type(4)));
typedef short bf16x8 __attribute__((ext_vector_type(8)));
typedef float f32x4 __attribute__((ext_vector_type(4)));

static __device__ inline unsigned short f2bf(float f) {
    unsigned u = __builtin_bit_cast(unsigned, f);
    u += 0x7fffu + ((u >> 16) & 1u);          // RNE
    return (unsigned short)(u >> 16);
}
// pack (lo=a, hi=b) as 2xbf16 in one u32 (RNE via HW cvt_pk)
static __device__ inline unsigned pack2(float a, float b) {
    unsigned u;
    asm("v_cvt_pk_bf16_f32 %0, %1, %2" : "=v"(u) : "v"(a), "v"(b));
    return u;
}
static __device__ inline float bflo(unsigned u) {
    return __builtin_bit_cast(float, u << 16);
}
static __device__ inline float bfhi(unsigned u) {
    return __builtin_bit_cast(float, u & 0xffff0000u);
}

// ---------------- prep: wg [128][64][3] f32 -> wT [2][3][64][64] bf16 ----------------
__global__ __launch_bounds__(256) void prep_wT(const float* __restrict__ wg,
                                               unsigned short* __restrict__ wT) {
    const int e = blockIdx.x * 256 + threadIdx.x;   // 24576 total
    if (e >= 24576) return;
    const int g   = e / 12288;
    const int rem = e - g * 12288;
    const int tap = rem >> 12;
    const int o   = (rem >> 6) & 63;
    const int ci  = rem & 63;
    wT[e] = f2bf(wg[((size_t)(g * 64 + o) * 64 + ci) * 3 + tap]);
}

// ---------------- Kernel A1: conv (bf16 MFMA) -> pools ONLY (no y store) -----------
// Block bx in [0,512): family f = bx&31 (g = f&1, b = f>>1), wq = bx>>5.
// Same-family blocks share bx%8 -> same XCD -> halo loads L2-hit.
// 64 o x 32 w x all 32 h per block. A = x (LDS [34][144]B), B = weights (regs).
// Emits: pool-H complete (pool2), pool-W 16-way partial (pool3p, u32 bf16x2),
// pool-C 2-way partial (pool1p, u32 bf16x2).
__global__ __launch_bounds__(256) void conv_pools(
    const float* __restrict__ x, const unsigned short* __restrict__ wT,
    unsigned* __restrict__ pool3p, unsigned* __restrict__ pool1p,
    float* __restrict__ pool2) {
    __shared__ __align__(16) char xsb[2][34 * 144];   // 9,792 B
    __shared__ float pcm[4 * 32];
    __shared__ float pcs[4 * 32];

    const int bx = blockIdx.x;
    const int f  = bx & 31;
    const int g  = f & 1;
    const int b  = f >> 1;
    const int wq = bx >> 5;
    const int t  = threadIdx.x;
    const int lane = t & 63;
    const int col  = lane & 15;
    const int q    = lane >> 4;
    const int wave = t >> 6;

    // ---- weight B-fragments ----
    const unsigned short* wA =
        wT + (size_t)g * 12288 + wave * 1024 + col * 64 + q * 8;
    bf16x8 wfr[3][2];
#pragma unroll
    for (int tap = 0; tap < 3; ++tap)
#pragma unroll
        for (int kk = 0; kk < 2; ++kk)
            wfr[tap][kk] = *(const bf16x8*)(wA + tap * 4096 + kk * 32);

    // ---- staging state: thread stages 2 ci x 4 w ----
    float a[2][4];
    float hv = 0.f;
    const int w0l = (t & 7) * 4;
    const int ci0 = (t >> 3) * 2;
    const float* xb0 = x + (size_t)(b * C + g * 64 + ci0) * (H * W) + wq * 32 + w0l;
    const int side = (t >> 6) & 1;
    const int hci  = t & 63;
    const int gw   = wq * 32 + (side ? 32 : -1);
    const bool hvalid = (t < 128) && (side ? (wq < 15) : (wq > 0));
    const float* xh0 = x + (size_t)(b * C + g * 64 + hci) * (H * W) + gw;

    auto LOADX = [&](int h) {
        const float4 v0 = *(const float4*)(xb0 + h * W);
        const float4 v1 = *(const float4*)(xb0 + (size_t)(H * W) + h * W);
        a[0][0] = v0.x; a[0][1] = v0.y; a[0][2] = v0.z; a[0][3] = v0.w;
        a[1][0] = v1.x; a[1][1] = v1.y; a[1][2] = v1.z; a[1][3] = v1.w;
        hv = hvalid ? xh0[h * W] : 0.f;
    };
    auto WRITEX = [&](char* buf) {
#pragma unroll
        for (int j = 0; j < 4; ++j)
            *(unsigned*)(buf + (size_t)(w0l + j + 1) * 144 + ci0 * 2) =
                pack2(a[0][j], a[1][j]);
        if (t < 128)
            *(unsigned short*)(buf + (size_t)(side ? 33 : 0) * 144 + hci * 2) = f2bf(hv);
    };

    // ---- pool-H accumulators ----
    f32x4 mH[2], sH[2];
#pragma unroll
    for (int wt = 0; wt < 2; ++wt) {
        mH[wt] = (f32x4){-INFINITY, -INFINITY, -INFINITY, -INFINITY};
        sH[wt] = (f32x4){0.f, 0.f, 0.f, 0.f};
    }

    LOADX(0);
    WRITEX(xsb[0]);
    LOADX(1);
    __syncthreads();

    for (int h = 0; h < H; ++h) {
        const int cur = h & 1;

        f32x4 acc[2];
        acc[0] = (f32x4){0.f, 0.f, 0.f, 0.f};
        acc[1] = (f32x4){0.f, 0.f, 0.f, 0.f};
        {
            const char* ab = xsb[cur] + q * 16;
#pragma unroll
            for (int wt = 0; wt < 2; ++wt)
#pragma unroll
                for (int kk = 0; kk < 2; ++kk)
#pragma unroll
                    for (int tap = 0; tap < 3; ++tap) {
                        const bf16x8 xf = *(const bf16x8*)(
                            ab + (size_t)(wt * 16 + col + tap) * 144 + kk * 64);
                        acc[wt] = __builtin_amdgcn_mfma_f32_16x16x32_bf16(
                            xf, wfr[tap][kk], acc[wt], 0, 0, 0);
                    }
        }

        // ---- pool-H accumulate ----
#pragma unroll
        for (int wt = 0; wt < 2; ++wt)
#pragma unroll
            for (int r = 0; r < 4; ++r) {
                mH[wt][r] = fmaxf(mH[wt][r], acc[wt][r]);
                sH[wt][r] += acc[wt][r];
            }

        // ---- pool-W (32 w of this block, per o) -> pool3p ----
        {
            float m = acc[0][0], s = acc[0][0];
            m = fmaxf(fmaxf(m, acc[0][1]), fmaxf(acc[0][2], acc[0][3]));
            s += acc[0][1] + acc[0][2] + acc[0][3];
#pragma unroll
            for (int r = 0; r < 4; ++r) {
                m = fmaxf(m, acc[1][r]);
                s += acc[1][r];
            }
            m = fmaxf(m, __shfl_xor(m, 16)); s += __shfl_xor(s, 16);
            m = fmaxf(m, __shfl_xor(m, 32)); s += __shfl_xor(s, 32);
            if (lane < 16)
                pool3p[((size_t)(wq * B + b) * H + h) * C + g * 64 + wave * 16 + lane] =
                    pack2(m, s);
        }
        // ---- pool-C (this wave's 16 o, per w) ----
        {
            float cm[2][4], cs[2][4];
#pragma unroll
            for (int wt = 0; wt < 2; ++wt)
#pragma unroll
                for (int r = 0; r < 4; ++r) { cm[wt][r] = acc[wt][r]; cs[wt][r] = acc[wt][r]; }
#pragma unroll
            for (int off = 1; off <= 8; off <<= 1)
#pragma unroll
                for (int wt = 0; wt < 2; ++wt)
#pragma unroll
                    for (int r = 0; r < 4; ++r) {
                        cm[wt][r] = fmaxf(cm[wt][r], __shfl_xor(cm[wt][r], off));
                        cs[wt][r] += __shfl_xor(cs[wt][r], off);
                    }
            if (col == 0)
#pragma unroll
                for (int wt = 0; wt < 2; ++wt)
#pragma unroll
                    for (int r = 0; r < 4; ++r) {
                        pcm[wave * 32 + wt * 16 + q * 4 + r] = cm[wt][r];
                        pcs[wave * 32 + wt * 16 + q * 4 + r] = cs[wt][r];
                    }
        }

        if (h < H - 1) WRITEX(xsb[cur ^ 1]);
        if (h < H - 2) LOADX(h + 2);
        __syncthreads();

        if (t < 32) {
            float m0 = pcm[t], s0 = pcs[t];
#pragma unroll
            for (int ot = 1; ot < 4; ++ot) {
                m0 = fmaxf(m0, pcm[ot * 32 + t]);
                s0 += pcs[ot * 32 + t];
            }
            pool1p[((size_t)(g * B + b) * H + h) * W + wq * 32 + t] = pack2(m0, s0);
        }
        __syncthreads();
    }

    // ---- pool-H final write -> pool2 [B,2,C,W] ----
    {
        const int o = g * 64 + wave * 16 + col;
        float* p2m = pool2 + ((size_t)(b * 2 + 0) * C + o) * W + wq * 32 + q * 4;
        float* p2s = pool2 + ((size_t)(b * 2 + 1) * C + o) * W + wq * 32 + q * 4;
#pragma unroll
        for (int wt = 0; wt < 2; ++wt) {
            *(f32x4*)(p2m + wt * 16) = mH[wt];
            f32x4 sv = sH[wt];
            sv[0] *= (1.f / H); sv[1] *= (1.f / H);
            sv[2] *= (1.f / H); sv[3] *= (1.f / H);
            *(f32x4*)(p2s + wt * 16) = sv;
        }
    }
}

// ---------------- Kernel A2: conv recompute + gate multiply -> out ----------------
// Same geometry/swizzle as A1. One barrier per h. out = y * (s1+s2+s3)/3.
__global__ __launch_bounds__(256) void conv_apply(
    const float* __restrict__ x, const unsigned short* __restrict__ wT,
    const float* __restrict__ s1, const float* __restrict__ s2,
    const float* __restrict__ s3, float* __restrict__ out) {
    __shared__ __align__(16) char xsb[2][34 * 144];   // 9,792 B

    const int bx = blockIdx.x;
    const int f  = bx & 31;
    const int g  = f & 1;
    const int b  = f >> 1;
    const int wq = bx >> 5;
    const int t  = threadIdx.x;
    const int lane = t & 63;
    const int col  = lane & 15;
    const int q    = lane >> 4;
    const int wave = t >> 6;

    const unsigned short* wA =
        wT + (size_t)g * 12288 + wave * 1024 + col * 64 + q * 8;
    bf16x8 wfr[3][2];
#pragma unroll
    for (int tap = 0; tap < 3; ++tap)
#pragma unroll
        for (int kk = 0; kk < 2; ++kk)
            wfr[tap][kk] = *(const bf16x8*)(wA + tap * 4096 + kk * 32);

    float a[2][4];
    float hv = 0.f;
    const int w0l = (t & 7) * 4;
    const int ci0 = (t >> 3) * 2;
    const float* xb0 = x + (size_t)(b * C + g * 64 + ci0) * (H * W) + wq * 32 + w0l;
    const int side = (t >> 6) & 1;
    const int hci  = t & 63;
    const int gw   = wq * 32 + (side ? 32 : -1);
    const bool hvalid = (t < 128) && (side ? (wq < 15) : (wq > 0));
    const float* xh0 = x + (size_t)(b * C + g * 64 + hci) * (H * W) + gw;

    auto LOADX = [&](int h) {
        const float4 v0 = *(const float4*)(xb0 + h * W);
        const float4 v1 = *(const float4*)(xb0 + (size_t)(H * W) + h * W);
        a[0][0] = v0.x; a[0][1] = v0.y; a[0][2] = v0.z; a[0][3] = v0.w;
        a[1][0] = v1.x; a[1][1] = v1.y; a[1][2] = v1.z; a[1][3] = v1.w;
        hv = hvalid ? xh0[h * W] : 0.f;
    };
    auto WRITEX = [&](char* buf) {
#pragma unroll
        for (int j = 0; j < 4; ++j)
            *(unsigned*)(buf + (size_t)(w0l + j + 1) * 144 + ci0 * 2) =
                pack2(a[0][j], a[1][j]);
        if (t < 128)
            *(unsigned short*)(buf + (size_t)(side ? 33 : 0) * 144 + hci * 2) = f2bf(hv);
    };

    // ---- hoisted gates: s2[b, o, w] (h-independent) ----
    const int o = g * 64 + wave * 16 + col;
    const float4 g2a = *(const float4*)(s2 + ((size_t)b * C + o) * W + wq * 32 + q * 4);
    const float4 g2b = *(const float4*)(s2 + ((size_t)b * C + o) * W + wq * 32 + q * 4 + 16);

    LOADX(0);
    WRITEX(xsb[0]);
    LOADX(1);
    __syncthreads();

    for (int h = 0; h < H; ++h) {
        const int cur = h & 1;

        f32x4 acc[2];
        acc[0] = (f32x4){0.f, 0.f, 0.f, 0.f};
        acc[1] = (f32x4){0.f, 0.f, 0.f, 0.f};
        {
            const char* ab = xsb[cur] + q * 16;
#pragma unroll
            for (int wt = 0; wt < 2; ++wt)
#pragma unroll
                for (int kk = 0; kk < 2; ++kk)
#pragma unroll
                    for (int tap = 0; tap < 3; ++tap) {
                        const bf16x8 xf = *(const bf16x8*)(
                            ab + (size_t)(wt * 16 + col + tap) * 144 + kk * 64);
                        acc[wt] = __builtin_amdgcn_mfma_f32_16x16x32_bf16(
                            xf, wfr[tap][kk], acc[wt], 0, 0, 0);
                    }
        }

        // ---- gates for this h ----
        const float4 g1a = *(const float4*)(s1 + ((size_t)b * H + h) * W + wq * 32 + q * 4);
        const float4 g1b = *(const float4*)(s1 + ((size_t)b * H + h) * W + wq * 32 + q * 4 + 16);
        const float  g3v = s3[((size_t)b * H + h) * C + o];
        const float  k   = 1.f / 3.f;

        float* ob = out + ((size_t)(b * C + o) * H + h) * W + wq * 32 + q * 4;
        f32x4 o0, o1;
        o0[0] = acc[0][0] * (g1a.x + g2a.x + g3v) * k;
        o0[1] = acc[0][1] * (g1a.y + g2a.y + g3v) * k;
        o0[2] = acc[0][2] * (g1a.z + g2a.z + g3v) * k;
        o0[3] = acc[0][3] * (g1a.w + g2a.w + g3v) * k;
        o1[0] = acc[1][0] * (g1b.x + g2b.x + g3v) * k;
        o1[1] = acc[1][1] * (g1b.y + g2b.y + g3v) * k;
        o1[2] = acc[1][2] * (g1b.z + g2b.z + g3v) * k;
        o1[3] = acc[1][3] * (g1b.w + g2b.w + g3v) * k;
        *(f32x4*)ob        = o0;
        *(f32x4*)(ob + 16) = o1;

        if (h < H - 1) WRITEX(xsb[cur ^ 1]);
        if (h < H - 2) LOADX(h + 2);
        __syncthreads();
    }
}

// ---------------- combine: pool1 (2-way) + pool3 (16-way) ----------------
__global__ __launch_bounds__(256) void combine(const unsigned* __restrict__ p1p,
                                               const unsigned* __restrict__ p3p,
                                               float* __restrict__ pool1,
                                               float* __restrict__ pool3) {
    const int bid = blockIdx.x;
    if (bid < 256) {
        const int n = bid * 256 + threadIdx.x;      // over B*H*W/4
        const int idx4 = n * 4;
        const uint4 u0 = *(const uint4*)(p1p + idx4);
        const uint4 u1 = *(const uint4*)(p1p + 262144 + idx4);
        const int b = idx4 >> 14;
        const int o = idx4 & 16383;
        float4 m, s;
        const float k = 1.f / C;
        m.x = fmaxf(bflo(u0.x), bflo(u1.x)); s.x = (bfhi(u0.x) + bfhi(u1.x)) * k;
        m.y = fmaxf(bflo(u0.y), bflo(u1.y)); s.y = (bfhi(u0.y) + bfhi(u1.y)) * k;
        m.z = fmaxf(bflo(u0.z), bflo(u1.z)); s.z = (bfhi(u0.z) + bfhi(u1.z)) * k;
        m.w = fmaxf(bflo(u0.w), bflo(u1.w)); s.w = (bfhi(u0.w) + bfhi(u1.w)) * k;
        *(float4*)(pool1 + ((size_t)(b * 2 + 0) * H * W) + o) = m;
        *(float4*)(pool1 + ((size_t)(b * 2 + 1) * H * W) + o) = s;
    } else {
        const int n = (bid - 256) * 256 + threadIdx.x;   // over B*H*C
        const int b = n >> 12;
        const int o = n & 4095;
        float m = -INFINITY, s = 0.f;
#pragma unroll
        for (int wq = 0; wq < 16; ++wq) {
            const unsigned u = p3p[(size_t)(wq * B + b) * 4096 + o];
            m = fmaxf(m, bflo(u));
            s += bfhi(u);
        }
        pool3[((size_t)(b * 2 + 0) * H * C) + o] = m;
        pool3[((size_t)(b * 2 + 1) * H * C) + o] = s * (1.f / W);
    }
}

// ---------------- gates: three 7x7 conv (2->1) + sigmoid in one kernel ------------
__global__ __launch_bounds__(256) void gates(
    const float* __restrict__ pool1, const float* __restrict__ pool2,
    const float* __restrict__ pool3, const float* __restrict__ w1,
    const float* __restrict__ w2, const float* __restrict__ w3,
    float* __restrict__ s1, float* __restrict__ s2, float* __restrict__ s3) {
    const int bid = blockIdx.x;
    const float* pin; const float* wgt; float* so; int P, Q, n;
    if (bid < 256)       { pin = pool1; wgt = w1; so = s1; P = H; Q = W;
                           n = bid * 256 + threadIdx.x; }
    else if (bid < 1280) { pin = pool2; wgt = w2; so = s2; P = C; Q = W;
                           n = (bid - 256) * 256 + threadIdx.x; }
    else                 { pin = pool3; wgt = w3; so = s3; P = H; Q = C;
                           n = (bid - 1280) * 256 + threadIdx.x; }
    const int q4   = Q >> 2;
    const int q0   = (n % q4) * 4;
    const int rest = n / q4;
    const int p    = rest % P;
    const int b    = rest / P;
    float acc0 = 0.f, acc1 = 0.f, acc2 = 0.f, acc3 = 0.f;
#pragma unroll
    for (int c2 = 0; c2 < 2; ++c2) {
#pragma unroll
        for (int i = 0; i < 7; ++i) {
            const int pp = p + i - 3;
            if (pp < 0 || pp >= P) continue;
            const float* row = pin + ((size_t)(b * 2 + c2) * P + pp) * Q;
            float win[10];
#pragma unroll
            for (int j = 0; j < 10; ++j) {
                const int qq = q0 + j - 3;
                win[j] = (qq >= 0 && qq < Q) ? row[qq] : 0.f;
            }
            const float* wr = wgt + c2 * 49 + i * 7;
#pragma unroll
            for (int j = 0; j < 7; ++j) {
                const float wv = wr[j];
                acc0 += win[j]     * wv;
                acc1 += win[j + 1] * wv;
                acc2 += win[j + 2] * wv;
                acc3 += win[j + 3] * wv;
            }
        }
    }
    float4 o;
    o.x = 1.f / (1.f + expf(-acc0));
    o.y = 1.f / (1.f + expf(-acc1));
    o.z = 1.f / (1.f + expf(-acc2));
    o.w = 1.f / (1.f + expf(-acc3));
    *(float4*)(so + (size_t)n * 4) = o;
}

extern "C" void kernel_launch(void* const* d_in, const int* in_sizes, int n_in,
                              void* d_out, int out_size, void* d_ws, size_t ws_size,
                              hipStream_t stream) {
    const float* x  = (const float*)d_in[0];
    const float* wg = (const float*)d_in[1];
    const float* w1 = (const float*)d_in[2];
    const float* w2 = (const float*)d_in[3];
    const float* w3 = (const float*)d_in[4];
    float* out = (float*)d_out;
    float* ws  = (float*)d_ws;

    // Workspace (float-slot offsets), total 4,337,664 floats = 17.35 MB:
    //  [0,       524288): pool1p u32 [2][B][H][W]   -> after combine: s1@0, s3@262144
    //  [524288, 1572864): pool3p u32 [16][B][H][C]  -> after combine: s2@524288
    //  [1572864,3670016): pool2 f32 [B][2][C][W]
    //  [3670016,4194304): pool1 f32 [B][2][H][W]
    //  [4194304,4325376): pool3 f32 [B][2][H][C]
    //  [4325376,4337664): wT (24576 bf16)
    unsigned* pool1p = (unsigned*)ws;
    unsigned* pool3p = (unsigned*)(ws + 524288);
    float* pool2 = ws + 1572864;
    float* pool1 = ws + 3670016;
    float* pool3 = ws + 4194304;
    unsigned short* wT = (unsigned short*)(ws + 4325376);
    float* s1 = ws;
    float* s3 = ws + 262144;
    float* s2 = ws + 524288;

    prep_wT<<<dim3(96), 256, 0, stream>>>(wg, wT);
    conv_pools<<<dim3(512), 256, 0, stream>>>(x, wT, pool3p, pool1p, pool2);
    combine<<<dim3(512), 256, 0, stream>>>(pool1p, pool3p, pool1, pool3);
    gates<<<dim3(1344), 256, 0, stream>>>(pool1, pool2, pool3, w1, w2, w3, s1, s2, s3);
    conv_apply<<<dim3(512), 256, 0, stream>>>(x, wT, s1, s2, s3, out);
}

// Round 11
// 156.939 us; speedup vs baseline: 1.3358x; 1.1293x over previous
//
#include <hip/hip_runtime.h>
#include <math.h>

#define B 16
#define C 128
#define H 32
#define W 512

typedef short bf16x4 __attribute__((ext_vector_type(4)));
typedef short bf16x8 __attribute__((ext_vector_type(8)));
typedef float f32x4 __attribute__((ext_vector_type(4)));

static __device__ inline unsigned short f2bf(float f) {
    unsigned u = __builtin_bit_cast(unsigned, f);
    u += 0x7fffu + ((u >> 16) & 1u);          // RNE
    return (unsigned short)(u >> 16);
}
// pack (lo=a, hi=b) as 2xbf16 in one u32 (RNE via HW cvt_pk)
static __device__ inline unsigned pack2(float a, float b) {
    unsigned u;
    asm("v_cvt_pk_bf16_f32 %0, %1, %2" : "=v"(u) : "v"(a), "v"(b));
    return u;
}
static __device__ inline float bflo(unsigned u) {
    return __builtin_bit_cast(float, u << 16);
}
static __device__ inline float bfhi(unsigned u) {
    return __builtin_bit_cast(float, u & 0xffff0000u);
}

// ---------------- prep: wg [128][64][3] f32 -> wT [2][3][64][64] bf16 ----------------
__global__ __launch_bounds__(256) void prep_wT(const float* __restrict__ wg,
                                               unsigned short* __restrict__ wT) {
    const int e = blockIdx.x * 256 + threadIdx.x;   // 24576 total
    if (e >= 24576) return;
    const int g   = e / 12288;
    const int rem = e - g * 12288;
    const int tap = rem >> 12;
    const int o   = (rem >> 6) & 63;
    const int ci  = rem & 63;
    wT[e] = f2bf(wg[((size_t)(g * 64 + o) * 64 + ci) * 3 + tap]);
}

// ---------------- Kernel A1: conv (bf16 MFMA) -> pools ONLY -----------------------
// Block bx in [0,512): family f = bx&31 (g = f&1, b = f>>1), wq = bx>>5.
// 64 o x 32 w x all 32 h. ONE barrier per h. Pool-C via LDS transpose (ytile dbuf),
// not shuffle-reduce. Emits pool2 (complete), pool3p (16-way), pool1p (2-way).
__global__ __launch_bounds__(256) void conv_pools(
    const float* __restrict__ x, const unsigned short* __restrict__ wT,
    unsigned* __restrict__ pool3p, unsigned* __restrict__ pool1p,
    float* __restrict__ pool2) {
    __shared__ __align__(16) char xsb[2][34 * 144];   // 9,792 B
    __shared__ __align__(16) float ytile[2][32][68];  // 17,408 B

    const int bx = blockIdx.x;
    const int f  = bx & 31;
    const int g  = f & 1;
    const int b  = f >> 1;
    const int wq = bx >> 5;
    const int t  = threadIdx.x;
    const int lane = t & 63;
    const int col  = lane & 15;
    const int q    = lane >> 4;
    const int wave = t >> 6;

    // ---- weight B-fragments ----
    const unsigned short* wA =
        wT + (size_t)g * 12288 + wave * 1024 + col * 64 + q * 8;
    bf16x8 wfr[3][2];
#pragma unroll
    for (int tap = 0; tap < 3; ++tap)
#pragma unroll
        for (int kk = 0; kk < 2; ++kk)
            wfr[tap][kk] = *(const bf16x8*)(wA + tap * 4096 + kk * 32);

    // ---- staging state: thread stages 2 ci x 4 w ----
    float a[2][4];
    float hv = 0.f;
    const int w0l = (t & 7) * 4;
    const int ci0 = (t >> 3) * 2;
    const float* xb0 = x + (size_t)(b * C + g * 64 + ci0) * (H * W) + wq * 32 + w0l;
    const int side = (t >> 6) & 1;
    const int hci  = t & 63;
    const int gw   = wq * 32 + (side ? 32 : -1);
    const bool hvalid = (t < 128) && (side ? (wq < 15) : (wq > 0));
    const float* xh0 = x + (size_t)(b * C + g * 64 + hci) * (H * W) + gw;

    auto LOADX = [&](int h) {
        const float4 v0 = *(const float4*)(xb0 + h * W);
        const float4 v1 = *(const float4*)(xb0 + (size_t)(H * W) + h * W);
        a[0][0] = v0.x; a[0][1] = v0.y; a[0][2] = v0.z; a[0][3] = v0.w;
        a[1][0] = v1.x; a[1][1] = v1.y; a[1][2] = v1.z; a[1][3] = v1.w;
        hv = hvalid ? xh0[h * W] : 0.f;
    };
    auto WRITEX = [&](char* buf) {
#pragma unroll
        for (int j = 0; j < 4; ++j)
            *(unsigned*)(buf + (size_t)(w0l + j + 1) * 144 + ci0 * 2) =
                pack2(a[0][j], a[1][j]);
        if (t < 128)
            *(unsigned short*)(buf + (size_t)(side ? 33 : 0) * 144 + hci * 2) = f2bf(hv);
    };

    // ---- pool-H accumulators ----
    f32x4 mH[2], sH[2];
#pragma unroll
    for (int wt = 0; wt < 2; ++wt) {
        mH[wt] = (f32x4){-INFINITY, -INFINITY, -INFINITY, -INFINITY};
        sH[wt] = (f32x4){0.f, 0.f, 0.f, 0.f};
    }

    // pool-C read assignment: 8 threads per w
    const int wl = t >> 3;              // w_local 0..31
    const int e  = t & 7;               // o-octet

    LOADX(0);
    WRITEX(xsb[0]);
    LOADX(1);
    __syncthreads();

    for (int h = 0; h < H; ++h) {
        const int cur = h & 1;

        f32x4 acc[2];
        acc[0] = (f32x4){0.f, 0.f, 0.f, 0.f};
        acc[1] = (f32x4){0.f, 0.f, 0.f, 0.f};
        {
            const char* ab = xsb[cur] + q * 16;
#pragma unroll
            for (int wt = 0; wt < 2; ++wt)
#pragma unroll
                for (int kk = 0; kk < 2; ++kk)
#pragma unroll
                    for (int tap = 0; tap < 3; ++tap) {
                        const bf16x8 xf = *(const bf16x8*)(
                            ab + (size_t)(wt * 16 + col + tap) * 144 + kk * 64);
                        acc[wt] = __builtin_amdgcn_mfma_f32_16x16x32_bf16(
                            xf, wfr[tap][kk], acc[wt], 0, 0, 0);
                    }
        }

        // ---- pool-H accumulate (regs) ----
#pragma unroll
        for (int wt = 0; wt < 2; ++wt)
#pragma unroll
            for (int r = 0; r < 4; ++r) {
                mH[wt][r] = fmaxf(mH[wt][r], acc[wt][r]);
                sH[wt][r] += acc[wt][r];
            }

        // ---- pool-W (32 w of this block, per o) -> pool3p ----
        {
            float m = acc[0][0], s = acc[0][0];
            m = fmaxf(fmaxf(m, acc[0][1]), fmaxf(acc[0][2], acc[0][3]));
            s += acc[0][1] + acc[0][2] + acc[0][3];
#pragma unroll
            for (int r = 0; r < 4; ++r) {
                m = fmaxf(m, acc[1][r]);
                s += acc[1][r];
            }
            m = fmaxf(m, __shfl_xor(m, 16)); s += __shfl_xor(s, 16);
            m = fmaxf(m, __shfl_xor(m, 32)); s += __shfl_xor(s, 32);
            if (lane < 16)
                pool3p[((size_t)(wq * B + b) * H + h) * C + g * 64 + wave * 16 + lane] =
                    pack2(m, s);
        }

        // ---- dump acc to ytile (column writes, 2-way bank = free) ----
#pragma unroll
        for (int wt = 0; wt < 2; ++wt)
#pragma unroll
            for (int r = 0; r < 4; ++r)
                ytile[cur][wt * 16 + q * 4 + r][wave * 16 + col] = acc[wt][r];

        // ---- pipeline stores/loads for h+1 / h+2 ----
        if (h < H - 1) WRITEX(xsb[cur ^ 1]);
        if (h < H - 2) LOADX(h + 2);
        __syncthreads();

        // ---- pool-C: 8 threads/w read the 64-o row, 3-round shuffle ----
        {
            const f32x4 v0 = *(const f32x4*)&ytile[cur][wl][e * 8];
            const f32x4 v1 = *(const f32x4*)&ytile[cur][wl][e * 8 + 4];
            float m = fmaxf(fmaxf(v0[0], v0[1]), fmaxf(v0[2], v0[3]));
            float s = v0[0] + v0[1] + v0[2] + v0[3];
            m = fmaxf(m, fmaxf(fmaxf(v1[0], v1[1]), fmaxf(v1[2], v1[3])));
            s += v1[0] + v1[1] + v1[2] + v1[3];
#pragma unroll
            for (int off = 1; off <= 4; off <<= 1) {
                m = fmaxf(m, __shfl_xor(m, off));
                s += __shfl_xor(s, off);
            }
            if (e == 0)
                pool1p[((size_t)(g * B + b) * H + h) * W + wq * 32 + wl] = pack2(m, s);
        }
    }

    // ---- pool-H final write -> pool2 [B,2,C,W] ----
    {
        const int o = g * 64 + wave * 16 + col;
        float* p2m = pool2 + ((size_t)(b * 2 + 0) * C + o) * W + wq * 32 + q * 4;
        float* p2s = pool2 + ((size_t)(b * 2 + 1) * C + o) * W + wq * 32 + q * 4;
#pragma unroll
        for (int wt = 0; wt < 2; ++wt) {
            *(f32x4*)(p2m + wt * 16) = mH[wt];
            f32x4 sv = sH[wt];
            sv[0] *= (1.f / H); sv[1] *= (1.f / H);
            sv[2] *= (1.f / H); sv[3] *= (1.f / H);
            *(f32x4*)(p2s + wt * 16) = sv;
        }
    }
}

// ---------------- Kernel A2: conv recompute + gate multiply -> out ----------------
// bx in [0,2048): f = bx&31 (g=f&1, b=f>>1), chunk = bx>>5: wq = chunk>>2, hq = chunk&3.
// 64 o x 32 w x 8 h. One barrier per h.
__global__ __launch_bounds__(256) void conv_apply(
    const float* __restrict__ x, const unsigned short* __restrict__ wT,
    const float* __restrict__ s1, const float* __restrict__ s2,
    const float* __restrict__ s3, float* __restrict__ out) {
    __shared__ __align__(16) char xsb[2][34 * 144];   // 9,792 B

    const int bx = blockIdx.x;
    const int f  = bx & 31;
    const int g  = f & 1;
    const int b  = f >> 1;
    const int chunk = bx >> 5;
    const int wq = chunk >> 2;
    const int hq = chunk & 3;
    const int h0 = hq * 8;
    const int t  = threadIdx.x;
    const int lane = t & 63;
    const int col  = lane & 15;
    const int q    = lane >> 4;
    const int wave = t >> 6;

    const unsigned short* wA =
        wT + (size_t)g * 12288 + wave * 1024 + col * 64 + q * 8;
    bf16x8 wfr[3][2];
#pragma unroll
    for (int tap = 0; tap < 3; ++tap)
#pragma unroll
        for (int kk = 0; kk < 2; ++kk)
            wfr[tap][kk] = *(const bf16x8*)(wA + tap * 4096 + kk * 32);

    float a[2][4];
    float hv = 0.f;
    const int w0l = (t & 7) * 4;
    const int ci0 = (t >> 3) * 2;
    const float* xb0 = x + (size_t)(b * C + g * 64 + ci0) * (H * W) + wq * 32 + w0l;
    const int side = (t >> 6) & 1;
    const int hci  = t & 63;
    const int gw   = wq * 32 + (side ? 32 : -1);
    const bool hvalid = (t < 128) && (side ? (wq < 15) : (wq > 0));
    const float* xh0 = x + (size_t)(b * C + g * 64 + hci) * (H * W) + gw;

    auto LOADX = [&](int h) {
        const float4 v0 = *(const float4*)(xb0 + h * W);
        const float4 v1 = *(const float4*)(xb0 + (size_t)(H * W) + h * W);
        a[0][0] = v0.x; a[0][1] = v0.y; a[0][2] = v0.z; a[0][3] = v0.w;
        a[1][0] = v1.x; a[1][1] = v1.y; a[1][2] = v1.z; a[1][3] = v1.w;
        hv = hvalid ? xh0[h * W] : 0.f;
    };
    auto WRITEX = [&](char* buf) {
#pragma unroll
        for (int j = 0; j < 4; ++j)
            *(unsigned*)(buf + (size_t)(w0l + j + 1) * 144 + ci0 * 2) =
                pack2(a[0][j], a[1][j]);
        if (t < 128)
            *(unsigned short*)(buf + (size_t)(side ? 33 : 0) * 144 + hci * 2) = f2bf(hv);
    };

    // ---- hoisted gates: s2[b, o, w] (h-independent) ----
    const int o = g * 64 + wave * 16 + col;
    const float4 g2a = *(const float4*)(s2 + ((size_t)b * C + o) * W + wq * 32 + q * 4);
    const float4 g2b = *(const float4*)(s2 + ((size_t)b * C + o) * W + wq * 32 + q * 4 + 16);

    LOADX(h0);
    WRITEX(xsb[0]);
    LOADX(h0 + 1);
    __syncthreads();

    for (int hh = 0; hh < 8; ++hh) {
        const int h   = h0 + hh;
        const int cur = hh & 1;

        f32x4 acc[2];
        acc[0] = (f32x4){0.f, 0.f, 0.f, 0.f};
        acc[1] = (f32x4){0.f, 0.f, 0.f, 0.f};
        {
            const char* ab = xsb[cur] + q * 16;
#pragma unroll
            for (int wt = 0; wt < 2; ++wt)
#pragma unroll
                for (int kk = 0; kk < 2; ++kk)
#pragma unroll
                    for (int tap = 0; tap < 3; ++tap) {
                        const bf16x8 xf = *(const bf16x8*)(
                            ab + (size_t)(wt * 16 + col + tap) * 144 + kk * 64);
                        acc[wt] = __builtin_amdgcn_mfma_f32_16x16x32_bf16(
                            xf, wfr[tap][kk], acc[wt], 0, 0, 0);
                    }
        }

        const float4 g1a = *(const float4*)(s1 + ((size_t)b * H + h) * W + wq * 32 + q * 4);
        const float4 g1b = *(const float4*)(s1 + ((size_t)b * H + h) * W + wq * 32 + q * 4 + 16);
        const float  g3v = s3[((size_t)b * H + h) * C + o];
        const float  k   = 1.f / 3.f;

        float* ob = out + ((size_t)(b * C + o) * H + h) * W + wq * 32 + q * 4;
        f32x4 o0, o1;
        o0[0] = acc[0][0] * (g1a.x + g2a.x + g3v) * k;
        o0[1] = acc[0][1] * (g1a.y + g2a.y + g3v) * k;
        o0[2] = acc[0][2] * (g1a.z + g2a.z + g3v) * k;
        o0[3] = acc[0][3] * (g1a.w + g2a.w + g3v) * k;
        o1[0] = acc[1][0] * (g1b.x + g2b.x + g3v) * k;
        o1[1] = acc[1][1] * (g1b.y + g2b.y + g3v) * k;
        o1[2] = acc[1][2] * (g1b.z + g2b.z + g3v) * k;
        o1[3] = acc[1][3] * (g1b.w + g2b.w + g3v) * k;
        *(f32x4*)ob        = o0;
        *(f32x4*)(ob + 16) = o1;

        if (hh < 7) WRITEX(xsb[cur ^ 1]);
        if (hh < 6) LOADX(h + 2);
        __syncthreads();
    }
}

// ---------------- combine: pool1 (2-way) + pool3 (16-way) ----------------
__global__ __launch_bounds__(256) void combine(const unsigned* __restrict__ p1p,
                                               const unsigned* __restrict__ p3p,
                                               float* __restrict__ pool1,
                                               float* __restrict__ pool3) {
    const int bid = blockIdx.x;
    if (bid < 256) {
        const int n = bid * 256 + threadIdx.x;      // over B*H*W/4
        const int idx4 = n * 4;
        const uint4 u0 = *(const uint4*)(p1p + idx4);
        const uint4 u1 = *(const uint4*)(p1p + 262144 + idx4);
        const int b = idx4 >> 14;
        const int o = idx4 & 16383;
        float4 m, s;
        const float k = 1.f / C;
        m.x = fmaxf(bflo(u0.x), bflo(u1.x)); s.x = (bfhi(u0.x) + bfhi(u1.x)) * k;
        m.y = fmaxf(bflo(u0.y), bflo(u1.y)); s.y = (bfhi(u0.y) + bfhi(u1.y)) * k;
        m.z = fmaxf(bflo(u0.z), bflo(u1.z)); s.z = (bfhi(u0.z) + bfhi(u1.z)) * k;
        m.w = fmaxf(bflo(u0.w), bflo(u1.w)); s.w = (bfhi(u0.w) + bfhi(u1.w)) * k;
        *(float4*)(pool1 + ((size_t)(b * 2 + 0) * H * W) + o) = m;
        *(float4*)(pool1 + ((size_t)(b * 2 + 1) * H * W) + o) = s;
    } else {
        const int n = (bid - 256) * 256 + threadIdx.x;   // over B*H*C
        const int b = n >> 12;
        const int o = n & 4095;
        float m = -INFINITY, s = 0.f;
#pragma unroll
        for (int wq = 0; wq < 16; ++wq) {
            const unsigned u = p3p[(size_t)(wq * B + b) * 4096 + o];
            m = fmaxf(m, bflo(u));
            s += bfhi(u);
        }
        pool3[((size_t)(b * 2 + 0) * H * C) + o] = m;
        pool3[((size_t)(b * 2 + 1) * H * C) + o] = s * (1.f / W);
    }
}

// ---------------- gates: three 7x7 conv (2->1) + sigmoid in one kernel ------------
__global__ __launch_bounds__(256) void gates(
    const float* __restrict__ pool1, const float* __restrict__ pool2,
    const float* __restrict__ pool3, const float* __restrict__ w1,
    const float* __restrict__ w2, const float* __restrict__ w3,
    float* __restrict__ s1, float* __restrict__ s2, float* __restrict__ s3) {
    const int bid = blockIdx.x;
    const float* pin; const float* wgt; float* so; int P, Q, n;
    if (bid < 256)       { pin = pool1; wgt = w1; so = s1; P = H; Q = W;
                           n = bid * 256 + threadIdx.x; }
    else if (bid < 1280) { pin = pool2; wgt = w2; so = s2; P = C; Q = W;
                           n = (bid - 256) * 256 + threadIdx.x; }
    else                 { pin = pool3; wgt = w3; so = s3; P = H; Q = C;
                           n = (bid - 1280) * 256 + threadIdx.x; }
    const int q4   = Q >> 2;
    const int q0   = (n % q4) * 4;
    const int rest = n / q4;
    const int p    = rest % P;
    const int b    = rest / P;
    float acc0 = 0.f, acc1 = 0.f, acc2 = 0.f, acc3 = 0.f;
#pragma unroll
    for (int c2 = 0; c2 < 2; ++c2) {
#pragma unroll
        for (int i = 0; i < 7; ++i) {
            const int pp = p + i - 3;
            if (pp < 0 || pp >= P) continue;
            const float* row = pin + ((size_t)(b * 2 + c2) * P + pp) * Q;
            float win[10];
#pragma unroll
            for (int j = 0; j < 10; ++j) {
                const int qq = q0 + j - 3;
                win[j] = (qq >= 0 && qq < Q) ? row[qq] : 0.f;
            }
            const float* wr = wgt + c2 * 49 + i * 7;
#pragma unroll
            for (int j = 0; j < 7; ++j) {
                const float wv = wr[j];
                acc0 += win[j]     * wv;
                acc1 += win[j + 1] * wv;
                acc2 += win[j + 2] * wv;
                acc3 += win[j + 3] * wv;
            }
        }
    }
    float4 o;
    o.x = 1.f / (1.f + expf(-acc0));
    o.y = 1.f / (1.f + expf(-acc1));
    o.z = 1.f / (1.f + expf(-acc2));
    o.w = 1.f / (1.f + expf(-acc3));
    *(float4*)(so + (size_t)n * 4) = o;
}

extern "C" void kernel_launch(void* const* d_in, const int* in_sizes, int n_in,
                              void* d_out, int out_size, void* d_ws, size_t ws_size,
                              hipStream_t stream) {
    const float* x  = (const float*)d_in[0];
    const float* wg = (const float*)d_in[1];
    const float* w1 = (const float*)d_in[2];
    const float* w2 = (const float*)d_in[3];
    const float* w3 = (const float*)d_in[4];
    float* out = (float*)d_out;
    float* ws  = (float*)d_ws;

    // Workspace (float-slot offsets), total 4,337,664 floats = 17.35 MB:
    //  [0,       524288): pool1p u32 [2][B][H][W]   -> after combine: s1@0, s3@262144
    //  [524288, 1572864): pool3p u32 [16][B][H][C]  -> after combine: s2@524288
    //  [1572864,3670016): pool2 f32 [B][2][C][W]
    //  [3670016,4194304): pool1 f32 [B][2][H][W]
    //  [4194304,4325376): pool3 f32 [B][2][H][C]
    //  [4325376,4337664): wT (24576 bf16)
    unsigned* pool1p = (unsigned*)ws;
    unsigned* pool3p = (unsigned*)(ws + 524288);
    float* pool2 = ws + 1572864;
    float* pool1 = ws + 3670016;
    float* pool3 = ws + 4194304;
    unsigned short* wT = (unsigned short*)(ws + 4325376);
    float* s1 = ws;
    float* s3 = ws + 262144;
    float* s2 = ws + 524288;

    prep_wT<<<dim3(96), 256, 0, stream>>>(wg, wT);
    conv_pools<<<dim3(512), 256, 0, stream>>>(x, wT, pool3p, pool1p, pool2);
    combine<<<dim3(512), 256, 0, stream>>>(pool1p, pool3p, pool1, pool3);
    gates<<<dim3(1344), 256, 0, stream>>>(pool1, pool2, pool3, w1, w2, w3, s1, s2, s3);
    conv_apply<<<dim3(2048), 256, 0, stream>>>(x, wT, s1, s2, s3, out);
}

// Round 12
// 135.521 us; speedup vs baseline: 1.5469x; 1.1580x over previous
//
#include <hip/hip_runtime.h>
#include <math.h>

#define B 16
#define C 128
#define H 32
#define W 512

typedef short bf16x4 __attribute__((ext_vector_type(4)));
typedef short bf16x8 __attribute__((ext_vector_type(8)));
typedef float f32x4 __attribute__((ext_vector_type(4)));

static __device__ inline unsigned short f2bf(float f) {
    unsigned u = __builtin_bit_cast(unsigned, f);
    u += 0x7fffu + ((u >> 16) & 1u);          // RNE
    return (unsigned short)(u >> 16);
}
// pack (lo=a, hi=b) as 2xbf16 in one u32 (RNE via HW cvt_pk)
static __device__ inline unsigned pack2(float a, float b) {
    unsigned u;
    asm("v_cvt_pk_bf16_f32 %0, %1, %2" : "=v"(u) : "v"(a), "v"(b));
    return u;
}
static __device__ inline float bflo(unsigned u) {
    return __builtin_bit_cast(float, u << 16);
}
static __device__ inline float bfhi(unsigned u) {
    return __builtin_bit_cast(float, u & 0xffff0000u);
}

// ---------------- prep: wg [128][64][3] f32 -> wT [2][3][64][64] bf16 ----------------
__global__ __launch_bounds__(256) void prep_wT(const float* __restrict__ wg,
                                               unsigned short* __restrict__ wT) {
    const int e = blockIdx.x * 256 + threadIdx.x;   // 24576 total
    if (e >= 24576) return;
    const int g   = e / 12288;
    const int rem = e - g * 12288;
    const int tap = rem >> 12;
    const int o   = (rem >> 6) & 63;
    const int ci  = rem & 63;
    wT[e] = f2bf(wg[((size_t)(g * 64 + o) * 64 + ci) * 3 + tap]);
}

// ---------------- Kernel A1: conv (bf16 MFMA) -> pools ONLY, h-split x2 -----------
// bx in [0,1024): f = bx&31 (g=f&1, b=f>>1), chunk = bx>>5: wq = chunk>>1, hq = chunk&1.
// 64 o x 32 w x 16 h. ONE barrier per h. Pool-C via LDS transpose (ytile dbuf).
// Emits pool2p (2-way h-partial, u32 bf16x2), pool3p (16-way), pool1p (2-way).
__global__ __launch_bounds__(256) void conv_pools(
    const float* __restrict__ x, const unsigned short* __restrict__ wT,
    unsigned* __restrict__ pool3p, unsigned* __restrict__ pool1p,
    unsigned* __restrict__ pool2p) {
    __shared__ __align__(16) char xsb[2][34 * 144];   // 9,792 B
    __shared__ __align__(16) float ytile[2][32][68];  // 17,408 B

    const int bx = blockIdx.x;
    const int f  = bx & 31;
    const int g  = f & 1;
    const int b  = f >> 1;
    const int chunk = bx >> 5;
    const int wq = chunk >> 1;
    const int hq = chunk & 1;
    const int h0 = hq * 16;
    const int t  = threadIdx.x;
    const int lane = t & 63;
    const int col  = lane & 15;
    const int q    = lane >> 4;
    const int wave = t >> 6;

    // ---- weight B-fragments ----
    const unsigned short* wA =
        wT + (size_t)g * 12288 + wave * 1024 + col * 64 + q * 8;
    bf16x8 wfr[3][2];
#pragma unroll
    for (int tap = 0; tap < 3; ++tap)
#pragma unroll
        for (int kk = 0; kk < 2; ++kk)
            wfr[tap][kk] = *(const bf16x8*)(wA + tap * 4096 + kk * 32);

    // ---- staging state: thread stages 2 ci x 4 w ----
    float a[2][4];
    float hv = 0.f;
    const int w0l = (t & 7) * 4;
    const int ci0 = (t >> 3) * 2;
    const float* xb0 = x + (size_t)(b * C + g * 64 + ci0) * (H * W) + wq * 32 + w0l;
    const int side = (t >> 6) & 1;
    const int hci  = t & 63;
    const int gw   = wq * 32 + (side ? 32 : -1);
    const bool hvalid = (t < 128) && (side ? (wq < 15) : (wq > 0));
    const float* xh0 = x + (size_t)(b * C + g * 64 + hci) * (H * W) + gw;

    auto LOADX = [&](int h) {
        const float4 v0 = *(const float4*)(xb0 + h * W);
        const float4 v1 = *(const float4*)(xb0 + (size_t)(H * W) + h * W);
        a[0][0] = v0.x; a[0][1] = v0.y; a[0][2] = v0.z; a[0][3] = v0.w;
        a[1][0] = v1.x; a[1][1] = v1.y; a[1][2] = v1.z; a[1][3] = v1.w;
        hv = hvalid ? xh0[h * W] : 0.f;
    };
    auto WRITEX = [&](char* buf) {
#pragma unroll
        for (int j = 0; j < 4; ++j)
            *(unsigned*)(buf + (size_t)(w0l + j + 1) * 144 + ci0 * 2) =
                pack2(a[0][j], a[1][j]);
        if (t < 128)
            *(unsigned short*)(buf + (size_t)(side ? 33 : 0) * 144 + hci * 2) = f2bf(hv);
    };

    // ---- pool-H accumulators (this chunk's 16 h) ----
    f32x4 mH[2], sH[2];
#pragma unroll
    for (int wt = 0; wt < 2; ++wt) {
        mH[wt] = (f32x4){-INFINITY, -INFINITY, -INFINITY, -INFINITY};
        sH[wt] = (f32x4){0.f, 0.f, 0.f, 0.f};
    }

    // pool-C read assignment: 8 threads per w
    const int wl = t >> 3;              // w_local 0..31
    const int e  = t & 7;               // o-octet

    LOADX(h0);
    WRITEX(xsb[0]);
    LOADX(h0 + 1);
    __syncthreads();

    for (int hh = 0; hh < 16; ++hh) {
        const int h   = h0 + hh;
        const int cur = hh & 1;

        f32x4 acc[2];
        acc[0] = (f32x4){0.f, 0.f, 0.f, 0.f};
        acc[1] = (f32x4){0.f, 0.f, 0.f, 0.f};
        {
            const char* ab = xsb[cur] + q * 16;
#pragma unroll
            for (int wt = 0; wt < 2; ++wt)
#pragma unroll
                for (int kk = 0; kk < 2; ++kk)
#pragma unroll
                    for (int tap = 0; tap < 3; ++tap) {
                        const bf16x8 xf = *(const bf16x8*)(
                            ab + (size_t)(wt * 16 + col + tap) * 144 + kk * 64);
                        acc[wt] = __builtin_amdgcn_mfma_f32_16x16x32_bf16(
                            xf, wfr[tap][kk], acc[wt], 0, 0, 0);
                    }
        }

        // ---- pool-H accumulate (regs) ----
#pragma unroll
        for (int wt = 0; wt < 2; ++wt)
#pragma unroll
            for (int r = 0; r < 4; ++r) {
                mH[wt][r] = fmaxf(mH[wt][r], acc[wt][r]);
                sH[wt][r] += acc[wt][r];
            }

        // ---- pool-W (32 w of this block, per o) -> pool3p ----
        {
            float m = acc[0][0], s = acc[0][0];
            m = fmaxf(fmaxf(m, acc[0][1]), fmaxf(acc[0][2], acc[0][3]));
            s += acc[0][1] + acc[0][2] + acc[0][3];
#pragma unroll
            for (int r = 0; r < 4; ++r) {
                m = fmaxf(m, acc[1][r]);
                s += acc[1][r];
            }
            m = fmaxf(m, __shfl_xor(m, 16)); s += __shfl_xor(s, 16);
            m = fmaxf(m, __shfl_xor(m, 32)); s += __shfl_xor(s, 32);
            if (lane < 16)
                pool3p[((size_t)(wq * B + b) * H + h) * C + g * 64 + wave * 16 + lane] =
                    pack2(m, s);
        }

        // ---- dump acc to ytile (column writes, 2-way bank = free) ----
#pragma unroll
        for (int wt = 0; wt < 2; ++wt)
#pragma unroll
            for (int r = 0; r < 4; ++r)
                ytile[cur][wt * 16 + q * 4 + r][wave * 16 + col] = acc[wt][r];

        // ---- pipeline stores/loads for h+1 / h+2 ----
        if (hh < 15) WRITEX(xsb[cur ^ 1]);
        if (hh < 14) LOADX(h + 2);
        __syncthreads();

        // ---- pool-C: 8 threads/w read the 64-o row, 3-round shuffle ----
        {
            const f32x4 v0 = *(const f32x4*)&ytile[cur][wl][e * 8];
            const f32x4 v1 = *(const f32x4*)&ytile[cur][wl][e * 8 + 4];
            float m = fmaxf(fmaxf(v0[0], v0[1]), fmaxf(v0[2], v0[3]));
            float s = v0[0] + v0[1] + v0[2] + v0[3];
            m = fmaxf(m, fmaxf(fmaxf(v1[0], v1[1]), fmaxf(v1[2], v1[3])));
            s += v1[0] + v1[1] + v1[2] + v1[3];
#pragma unroll
            for (int off = 1; off <= 4; off <<= 1) {
                m = fmaxf(m, __shfl_xor(m, off));
                s += __shfl_xor(s, off);
            }
            if (e == 0)
                pool1p[((size_t)(g * B + b) * H + h) * W + wq * 32 + wl] = pack2(m, s);
        }
    }

    // ---- pool-H partial write -> pool2p[hq][B][C][W] u32 (m, raw sum) ----
    {
        const int o = g * 64 + wave * 16 + col;
        unsigned* p2 = pool2p + ((size_t)(hq * B + b) * C + o) * W + wq * 32 + q * 4;
#pragma unroll
        for (int wt = 0; wt < 2; ++wt) {
            uint4 pk;
            pk.x = pack2(mH[wt][0], sH[wt][0]);
            pk.y = pack2(mH[wt][1], sH[wt][1]);
            pk.z = pack2(mH[wt][2], sH[wt][2]);
            pk.w = pack2(mH[wt][3], sH[wt][3]);
            *(uint4*)(p2 + wt * 16) = pk;
        }
    }
}

// ---------------- Kernel A2: conv recompute + gate multiply -> out ----------------
// bx in [0,2048): f = bx&31 (g=f&1, b=f>>1), chunk = bx>>5: wq = chunk>>2, hq = chunk&3.
// 64 o x 32 w x 8 h. One barrier per h.
__global__ __launch_bounds__(256) void conv_apply(
    const float* __restrict__ x, const unsigned short* __restrict__ wT,
    const float* __restrict__ s1, const float* __restrict__ s2,
    const float* __restrict__ s3, float* __restrict__ out) {
    __shared__ __align__(16) char xsb[2][34 * 144];   // 9,792 B

    const int bx = blockIdx.x;
    const int f  = bx & 31;
    const int g  = f & 1;
    const int b  = f >> 1;
    const int chunk = bx >> 5;
    const int wq = chunk >> 2;
    const int hq = chunk & 3;
    const int h0 = hq * 8;
    const int t  = threadIdx.x;
    const int lane = t & 63;
    const int col  = lane & 15;
    const int q    = lane >> 4;
    const int wave = t >> 6;

    const unsigned short* wA =
        wT + (size_t)g * 12288 + wave * 1024 + col * 64 + q * 8;
    bf16x8 wfr[3][2];
#pragma unroll
    for (int tap = 0; tap < 3; ++tap)
#pragma unroll
        for (int kk = 0; kk < 2; ++kk)
            wfr[tap][kk] = *(const bf16x8*)(wA + tap * 4096 + kk * 32);

    float a[2][4];
    float hv = 0.f;
    const int w0l = (t & 7) * 4;
    const int ci0 = (t >> 3) * 2;
    const float* xb0 = x + (size_t)(b * C + g * 64 + ci0) * (H * W) + wq * 32 + w0l;
    const int side = (t >> 6) & 1;
    const int hci  = t & 63;
    const int gw   = wq * 32 + (side ? 32 : -1);
    const bool hvalid = (t < 128) && (side ? (wq < 15) : (wq > 0));
    const float* xh0 = x + (size_t)(b * C + g * 64 + hci) * (H * W) + gw;

    auto LOADX = [&](int h) {
        const float4 v0 = *(const float4*)(xb0 + h * W);
        const float4 v1 = *(const float4*)(xb0 + (size_t)(H * W) + h * W);
        a[0][0] = v0.x; a[0][1] = v0.y; a[0][2] = v0.z; a[0][3] = v0.w;
        a[1][0] = v1.x; a[1][1] = v1.y; a[1][2] = v1.z; a[1][3] = v1.w;
        hv = hvalid ? xh0[h * W] : 0.f;
    };
    auto WRITEX = [&](char* buf) {
#pragma unroll
        for (int j = 0; j < 4; ++j)
            *(unsigned*)(buf + (size_t)(w0l + j + 1) * 144 + ci0 * 2) =
                pack2(a[0][j], a[1][j]);
        if (t < 128)
            *(unsigned short*)(buf + (size_t)(side ? 33 : 0) * 144 + hci * 2) = f2bf(hv);
    };

    // ---- hoisted gates: s2[b, o, w] (h-independent) ----
    const int o = g * 64 + wave * 16 + col;
    const float4 g2a = *(const float4*)(s2 + ((size_t)b * C + o) * W + wq * 32 + q * 4);
    const float4 g2b = *(const float4*)(s2 + ((size_t)b * C + o) * W + wq * 32 + q * 4 + 16);

    LOADX(h0);
    WRITEX(xsb[0]);
    LOADX(h0 + 1);
    __syncthreads();

    for (int hh = 0; hh < 8; ++hh) {
        const int h   = h0 + hh;
        const int cur = hh & 1;

        f32x4 acc[2];
        acc[0] = (f32x4){0.f, 0.f, 0.f, 0.f};
        acc[1] = (f32x4){0.f, 0.f, 0.f, 0.f};
        {
            const char* ab = xsb[cur] + q * 16;
#pragma unroll
            for (int wt = 0; wt < 2; ++wt)
#pragma unroll
                for (int kk = 0; kk < 2; ++kk)
#pragma unroll
                    for (int tap = 0; tap < 3; ++tap) {
                        const bf16x8 xf = *(const bf16x8*)(
                            ab + (size_t)(wt * 16 + col + tap) * 144 + kk * 64);
                        acc[wt] = __builtin_amdgcn_mfma_f32_16x16x32_bf16(
                            xf, wfr[tap][kk], acc[wt], 0, 0, 0);
                    }
        }

        const float4 g1a = *(const float4*)(s1 + ((size_t)b * H + h) * W + wq * 32 + q * 4);
        const float4 g1b = *(const float4*)(s1 + ((size_t)b * H + h) * W + wq * 32 + q * 4 + 16);
        const float  g3v = s3[((size_t)b * H + h) * C + o];
        const float  k   = 1.f / 3.f;

        float* ob = out + ((size_t)(b * C + o) * H + h) * W + wq * 32 + q * 4;
        f32x4 o0, o1;
        o0[0] = acc[0][0] * (g1a.x + g2a.x + g3v) * k;
        o0[1] = acc[0][1] * (g1a.y + g2a.y + g3v) * k;
        o0[2] = acc[0][2] * (g1a.z + g2a.z + g3v) * k;
        o0[3] = acc[0][3] * (g1a.w + g2a.w + g3v) * k;
        o1[0] = acc[1][0] * (g1b.x + g2b.x + g3v) * k;
        o1[1] = acc[1][1] * (g1b.y + g2b.y + g3v) * k;
        o1[2] = acc[1][2] * (g1b.z + g2b.z + g3v) * k;
        o1[3] = acc[1][3] * (g1b.w + g2b.w + g3v) * k;
        *(f32x4*)ob        = o0;
        *(f32x4*)(ob + 16) = o1;

        if (hh < 7) WRITEX(xsb[cur ^ 1]);
        if (hh < 6) LOADX(h + 2);
        __syncthreads();
    }
}

// ---------------- combine: pool1 (2-way) + pool3 (16-way) + pool2 (2-way) ---------
__global__ __launch_bounds__(256) void combine(const unsigned* __restrict__ p1p,
                                               const unsigned* __restrict__ p3p,
                                               unsigned* __restrict__ p2p,
                                               float* __restrict__ pool1,
                                               float* __restrict__ pool3) {
    const int bid = blockIdx.x;
    if (bid < 256) {
        const int n = bid * 256 + threadIdx.x;      // over B*H*W/4
        const int idx4 = n * 4;
        const uint4 u0 = *(const uint4*)(p1p + idx4);
        const uint4 u1 = *(const uint4*)(p1p + 262144 + idx4);
        const int b = idx4 >> 14;
        const int o = idx4 & 16383;
        float4 m, s;
        const float k = 1.f / C;
        m.x = fmaxf(bflo(u0.x), bflo(u1.x)); s.x = (bfhi(u0.x) + bfhi(u1.x)) * k;
        m.y = fmaxf(bflo(u0.y), bflo(u1.y)); s.y = (bfhi(u0.y) + bfhi(u1.y)) * k;
        m.z = fmaxf(bflo(u0.z), bflo(u1.z)); s.z = (bfhi(u0.z) + bfhi(u1.z)) * k;
        m.w = fmaxf(bflo(u0.w), bflo(u1.w)); s.w = (bfhi(u0.w) + bfhi(u1.w)) * k;
        *(float4*)(pool1 + ((size_t)(b * 2 + 0) * H * W) + o) = m;
        *(float4*)(pool1 + ((size_t)(b * 2 + 1) * H * W) + o) = s;
    } else if (bid < 512) {
        const int n = (bid - 256) * 256 + threadIdx.x;   // over B*H*C
        const int b = n >> 12;
        const int o = n & 4095;
        float m = -INFINITY, s = 0.f;
#pragma unroll
        for (int wq = 0; wq < 16; ++wq) {
            const unsigned u = p3p[(size_t)(wq * B + b) * 4096 + o];
            m = fmaxf(m, bflo(u));
            s += bfhi(u);
        }
        pool3[((size_t)(b * 2 + 0) * H * C) + o] = m;
        pool3[((size_t)(b * 2 + 1) * H * C) + o] = s * (1.f / W);
    } else {
        const int n = (bid - 512) * 256 + threadIdx.x;   // over B*C*W/4
        const int idx4 = n * 4;
        const uint4 u0 = *(const uint4*)(p2p + idx4);
        const uint4 u1 = *(const uint4*)(p2p + 1048576 + idx4);
        const float k = 1.f / H;
        uint4 r;
        r.x = pack2(fmaxf(bflo(u0.x), bflo(u1.x)), (bfhi(u0.x) + bfhi(u1.x)) * k);
        r.y = pack2(fmaxf(bflo(u0.y), bflo(u1.y)), (bfhi(u0.y) + bfhi(u1.y)) * k);
        r.z = pack2(fmaxf(bflo(u0.z), bflo(u1.z)), (bfhi(u0.z) + bfhi(u1.z)) * k);
        r.w = pack2(fmaxf(bflo(u0.w), bflo(u1.w)), (bfhi(u0.w) + bfhi(u1.w)) * k);
        *(uint4*)(p2p + idx4) = r;                       // in-place to chunk 0
    }
}

// ---------------- gates: three 7x7 conv (2->1) + sigmoid in one kernel ------------
// s2 branch reads the PACKED pool2 (u32 = {max lo, mean hi}) -> one load per tap.
__global__ __launch_bounds__(256) void gates(
    const float* __restrict__ pool1, const unsigned* __restrict__ pool2,
    const float* __restrict__ pool3, const float* __restrict__ w1,
    const float* __restrict__ w2, const float* __restrict__ w3,
    float* __restrict__ s1, float* __restrict__ s2, float* __restrict__ s3) {
    const int bid = blockIdx.x;
    if (bid >= 256 && bid < 1280) {
        // ---- s2: packed input, P=C, Q=W ----
        const int n  = (bid - 256) * 256 + threadIdx.x;   // over B*C*W/4
        const int q0 = (n & 127) * 4;
        const int p  = (n >> 7) & 127;
        const int b  = n >> 14;
        float acc0 = 0.f, acc1 = 0.f, acc2 = 0.f, acc3 = 0.f;
#pragma unroll
        for (int i = 0; i < 7; ++i) {
            const int pp = p + i - 3;
            if (pp < 0 || pp >= C) continue;
            const unsigned* row = pool2 + ((size_t)b * C + pp) * W;
            unsigned win[10];
#pragma unroll
            for (int j = 0; j < 10; ++j) {
                const int qq = q0 + j - 3;
                win[j] = (qq >= 0 && qq < W) ? row[qq] : 0u;
            }
            const float* wr0 = w2 + i * 7;        // channel 0 (max)
            const float* wr1 = w2 + 49 + i * 7;   // channel 1 (mean)
#pragma unroll
            for (int j = 0; j < 7; ++j) {
                const float wv0 = wr0[j], wv1 = wr1[j];
                acc0 += bflo(win[j])     * wv0 + bfhi(win[j])     * wv1;
                acc1 += bflo(win[j + 1]) * wv0 + bfhi(win[j + 1]) * wv1;
                acc2 += bflo(win[j + 2]) * wv0 + bfhi(win[j + 2]) * wv1;
                acc3 += bflo(win[j + 3]) * wv0 + bfhi(win[j + 3]) * wv1;
            }
        }
        float4 o;
        o.x = 1.f / (1.f + expf(-acc0));
        o.y = 1.f / (1.f + expf(-acc1));
        o.z = 1.f / (1.f + expf(-acc2));
        o.w = 1.f / (1.f + expf(-acc3));
        *(float4*)(s2 + (size_t)n * 4) = o;
        return;
    }
    const float* pin; const float* wgt; float* so; int P, Q, n;
    if (bid < 256) { pin = pool1; wgt = w1; so = s1; P = H; Q = W;
                     n = bid * 256 + threadIdx.x; }
    else           { pin = pool3; wgt = w3; so = s3; P = H; Q = C;
                     n = (bid - 1280) * 256 + threadIdx.x; }
    const int q4   = Q >> 2;
    const int q0   = (n % q4) * 4;
    const int rest = n / q4;
    const int p    = rest % P;
    const int b    = rest / P;
    float acc0 = 0.f, acc1 = 0.f, acc2 = 0.f, acc3 = 0.f;
#pragma unroll
    for (int c2 = 0; c2 < 2; ++c2) {
#pragma unroll
        for (int i = 0; i < 7; ++i) {
            const int pp = p + i - 3;
            if (pp < 0 || pp >= P) continue;
            const float* row = pin + ((size_t)(b * 2 + c2) * P + pp) * Q;
            float win[10];
#pragma unroll
            for (int j = 0; j < 10; ++j) {
                const int qq = q0 + j - 3;
                win[j] = (qq >= 0 && qq < Q) ? row[qq] : 0.f;
            }
            const float* wr = wgt + c2 * 49 + i * 7;
#pragma unroll
            for (int j = 0; j < 7; ++j) {
                const float wv = wr[j];
                acc0 += win[j]     * wv;
                acc1 += win[j + 1] * wv;
                acc2 += win[j + 2] * wv;
                acc3 += win[j + 3] * wv;
            }
        }
    }
    float4 o;
    o.x = 1.f / (1.f + expf(-acc0));
    o.y = 1.f / (1.f + expf(-acc1));
    o.z = 1.f / (1.f + expf(-acc2));
    o.w = 1.f / (1.f + expf(-acc3));
    *(float4*)(so + (size_t)n * 4) = o;
}

extern "C" void kernel_launch(void* const* d_in, const int* in_sizes, int n_in,
                              void* d_out, int out_size, void* d_ws, size_t ws_size,
                              hipStream_t stream) {
    const float* x  = (const float*)d_in[0];
    const float* wg = (const float*)d_in[1];
    const float* w1 = (const float*)d_in[2];
    const float* w2 = (const float*)d_in[3];
    const float* w3 = (const float*)d_in[4];
    float* out = (float*)d_out;
    float* ws  = (float*)d_ws;

    // Workspace (float-slot offsets), total 4,337,664 floats = 17.35 MB:
    //  [0,       524288): pool1p u32 [2][B][H][W]   -> after combine: s1@0, s3@262144
    //  [524288, 1572864): pool3p u32 [16][B][H][C]  -> after combine: s2@524288
    //  [1572864,3670016): pool2p u32 [2][B][C][W]   (chunk0 becomes combined pool2)
    //  [3670016,4194304): pool1 f32 [B][2][H][W]
    //  [4194304,4325376): pool3 f32 [B][2][H][C]
    //  [4325376,4337664): wT (24576 bf16)
    unsigned* pool1p = (unsigned*)ws;
    unsigned* pool3p = (unsigned*)(ws + 524288);
    unsigned* pool2p = (unsigned*)(ws + 1572864);
    float* pool1 = ws + 3670016;
    float* pool3 = ws + 4194304;
    unsigned short* wT = (unsigned short*)(ws + 4325376);
    float* s1 = ws;
    float* s3 = ws + 262144;
    float* s2 = ws + 524288;

    prep_wT<<<dim3(96), 256, 0, stream>>>(wg, wT);
    conv_pools<<<dim3(1024), 256, 0, stream>>>(x, wT, pool3p, pool1p, pool2p);
    combine<<<dim3(1536), 256, 0, stream>>>(pool1p, pool3p, pool2p, pool1, pool3);
    gates<<<dim3(1344), 256, 0, stream>>>(pool1, pool2p, pool3, w1, w2, w3, s1, s2, s3);
    conv_apply<<<dim3(2048), 256, 0, stream>>>(x, wT, s1, s2, s3, out);
}